// Round 1
// baseline (79.308 us; speedup 1.0000x reference)
//
#include <hip/hip_runtime.h>

// SpatiallyJitterColorChannels: per-(b,c) 2D roll of x[64,3,512,512] f32.
// out[b,c,h,w] = x[b,c,(h-sh)&511,(w-sw)&511], s = shifts[b,c,:] - SHIFT
#define SHIFT 2
#define H 512
#define W 512

__global__ __launch_bounds__(128)
void roll2d_kernel(const float* __restrict__ x,
                   const int* __restrict__ shifts,
                   float* __restrict__ out) {
    __shared__ float row[W];

    const int h  = blockIdx.x;        // 0..511
    const int bc = blockIdx.y;        // 0..191 (b*3+c)

    const int sh = shifts[2 * bc]     - SHIFT;  // [-2,2]
    const int sw = shifts[2 * bc + 1] - SHIFT;  // [-2,2]

    const int srcH = (h - sh) & (H - 1);        // mod works for small negatives (two's complement &)

    const float4* __restrict__ src =
        reinterpret_cast<const float4*>(x + ((size_t)bc * H + srcH) * W);
    float4* __restrict__ dst =
        reinterpret_cast<float4*>(out + ((size_t)bc * H + h) * W);

    const int t = threadIdx.x;        // 0..127, 4 elems each

    // Aligned, coalesced 16B/lane load of the source row into LDS.
    float4 v = src[t];
    row[4 * t + 0] = v.x;
    row[4 * t + 1] = v.y;
    row[4 * t + 2] = v.z;
    row[4 * t + 3] = v.w;
    __syncthreads();

    // Column roll via LDS, then aligned coalesced 16B/lane store.
    const int w0 = 4 * t;
    float4 o;
    o.x = row[(w0 + 0 - sw) & (W - 1)];
    o.y = row[(w0 + 1 - sw) & (W - 1)];
    o.z = row[(w0 + 2 - sw) & (W - 1)];
    o.w = row[(w0 + 3 - sw) & (W - 1)];
    dst[t] = o;
}

extern "C" void kernel_launch(void* const* d_in, const int* in_sizes, int n_in,
                              void* d_out, int out_size, void* d_ws, size_t ws_size,
                              hipStream_t stream) {
    const float* x      = (const float*)d_in[0];   // [64,3,512,512] f32
    const int*   shifts = (const int*)d_in[1];     // [64,3,2] i32
    float*       out    = (float*)d_out;           // [64,3,512,512] f32

    dim3 grid(H, 64 * 3);   // (h, b*c)
    dim3 block(128);
    roll2d_kernel<<<grid, block, 0, stream>>>(x, shifts, out);
}

// Round 2
// 76.794 us; speedup vs baseline: 1.0327x; 1.0327x over previous
//
#include <hip/hip_runtime.h>

// SpatiallyJitterColorChannels: per-(b,c) 2D roll of x[64,3,512,512] f32.
// out[b,c,h,w] = x[b,c,(h-sh)&511,(w-sw)&511], s = shifts[b,c,:] - SHIFT
#define SHIFT 2
#define H 512
#define W 512

// 256 threads = 4 waves; each wave independently handles 2 full rows.
// No __syncthreads: each wave only touches its own LDS row slots, and
// same-wave ds_write -> ds_read ordering is enforced via lgkmcnt.
//
// LDS layout per row (component-SoA): float f stored at (f&3)*128 + (f>>2).
//  - writes: component j of the loaded float4s -> addresses j*128 + {lane, 64+lane}
//    (stride-1 across lanes, conflict-free)
//  - shifted gather: idx = (4k + j - sw) & 511; (idx&3) = (j-sw)&3 is
//    wave-uniform, (idx>>2) is lane-stride-1 -> conflict-free (<=2-way).
__global__ __launch_bounds__(256)
void roll2d_kernel(const float* __restrict__ x,
                   const int* __restrict__ shifts,
                   float* __restrict__ out) {
    __shared__ float lds[8][4][W / 4];   // 16 KiB: [row-slot][comp][quad]

    const int tid  = threadIdx.x;
    const int wv   = tid >> 6;    // 0..3
    const int lane = tid & 63;
    const int bc   = blockIdx.y;  // 0..191 (b*3+c), block-uniform -> scalar loads

    const int sh = shifts[2 * bc]     - SHIFT;  // [-2,2]
    const int sw = shifts[2 * bc + 1] - SHIFT;  // [-2,2]

    const int r0 = wv * 2;
    const int r1 = r0 + 1;
    const int h0 = blockIdx.x * 8 + r0;
    const int h1 = h0 + 1;

    const size_t planeBase = (size_t)bc * H;

    const float4* s0 = reinterpret_cast<const float4*>(
        x + (planeBase + ((h0 - sh) & (H - 1))) * (size_t)W);
    const float4* s1 = reinterpret_cast<const float4*>(
        x + (planeBase + ((h1 - sh) & (H - 1))) * (size_t)W);

    // Issue all 4 row-half loads up front (ILP).
    float4 a0 = s0[lane];
    float4 a1 = s0[lane + 64];
    float4 b0 = s1[lane];
    float4 b1 = s1[lane + 64];

    float* L0 = &lds[r0][0][0];
    float* L1 = &lds[r1][0][0];

    // Row r0: floats 4*lane+j -> j*128 + lane ; floats 256+4*lane+j -> j*128 + 64 + lane
    L0[0 * 128 + lane]      = a0.x;
    L0[1 * 128 + lane]      = a0.y;
    L0[2 * 128 + lane]      = a0.z;
    L0[3 * 128 + lane]      = a0.w;
    L0[0 * 128 + 64 + lane] = a1.x;
    L0[1 * 128 + 64 + lane] = a1.y;
    L0[2 * 128 + 64 + lane] = a1.z;
    L0[3 * 128 + 64 + lane] = a1.w;

    L1[0 * 128 + lane]      = b0.x;
    L1[1 * 128 + lane]      = b0.y;
    L1[2 * 128 + lane]      = b0.z;
    L1[3 * 128 + lane]      = b0.w;
    L1[0 * 128 + 64 + lane] = b1.x;
    L1[1 * 128 + 64 + lane] = b1.y;
    L1[2 * 128 + 64 + lane] = b1.z;
    L1[3 * 128 + 64 + lane] = b1.w;

    auto gather = [&](const float* L, int k) -> float4 {
        const int base = 4 * k - sw;
        const int i0 = (base + 0) & (W - 1);
        const int i1 = (base + 1) & (W - 1);
        const int i2 = (base + 2) & (W - 1);
        const int i3 = (base + 3) & (W - 1);
        float4 o;
        o.x = L[((i0 & 3) << 7) | (i0 >> 2)];
        o.y = L[((i1 & 3) << 7) | (i1 >> 2)];
        o.z = L[((i2 & 3) << 7) | (i2 >> 2)];
        o.w = L[((i3 & 3) << 7) | (i3 >> 2)];
        return o;
    };

    float4* d0 = reinterpret_cast<float4*>(out + (planeBase + h0) * (size_t)W);
    float4* d1 = reinterpret_cast<float4*>(out + (planeBase + h1) * (size_t)W);

    d0[lane]      = gather(L0, lane);
    d0[lane + 64] = gather(L0, lane + 64);
    d1[lane]      = gather(L1, lane);
    d1[lane + 64] = gather(L1, lane + 64);
}

extern "C" void kernel_launch(void* const* d_in, const int* in_sizes, int n_in,
                              void* d_out, int out_size, void* d_ws, size_t ws_size,
                              hipStream_t stream) {
    const float* x      = (const float*)d_in[0];   // [64,3,512,512] f32
    const int*   shifts = (const int*)d_in[1];     // [64,3,2] i32
    float*       out    = (float*)d_out;           // [64,3,512,512] f32

    dim3 grid(H / 8, 64 * 3);   // 8 rows per block
    dim3 block(256);
    roll2d_kernel<<<grid, block, 0, stream>>>(x, shifts, out);
}